// Round 1
// baseline (433.013 us; speedup 1.0000x reference)
//
#include <hip/hip_runtime.h>
#include <hip/hip_fp16.h>
#include <type_traits>

#define NU 100000
#define NI 50000
#define NN 150000          // NU + NI (even)
#define HH 64
#define NE 1200000

#define SCAN_CHUNK 1024
#define NBLK ((NN + SCAN_CHUNK - 1) / SCAN_CHUNK)   // 147

// ---------------------------------------------------------------- degree histogram + rank
// rank[e] = this edge's ordinal among same-dst edges (atomicAdd return value).
// 8 edges/thread: 8 independent atomics in flight per thread (latency-bound op —
// throughput = in-flight / ~375ns round trip; 2x depth vs the 4/thread version).
// Block 0 also zeroes the Xs0 pad row (replaces a hipMemsetAsync dispatch).
__global__ __launch_bounds__(256) void k_rank(const int4* __restrict__ dst4,
                                              int* __restrict__ counts,
                                              int4* __restrict__ rank4,
                                              __half* __restrict__ xs_pad) {
    if (blockIdx.x == 0 && threadIdx.x < 8)
        ((int4*)xs_pad)[threadIdx.x] = make_int4(0, 0, 0, 0);
    int t = blockIdx.x * blockDim.x + threadIdx.x;   // over NE/8
    if (t >= NE / 8) return;
    int4 d0 = dst4[2 * t], d1 = dst4[2 * t + 1];
    int4 r0, r1;
    r0.x = atomicAdd(&counts[d0.x], 1);
    r0.y = atomicAdd(&counts[d0.y], 1);
    r0.z = atomicAdd(&counts[d0.z], 1);
    r0.w = atomicAdd(&counts[d0.w], 1);
    r1.x = atomicAdd(&counts[d1.x], 1);
    r1.y = atomicAdd(&counts[d1.y], 1);
    r1.z = atomicAdd(&counts[d1.z], 1);
    r1.w = atomicAdd(&counts[d1.w], 1);
    rank4[2 * t]     = r0;
    rank4[2 * t + 1] = r1;
}

// ---------------------------------------------------------------- single-pass scan (decoupled lookback)
// Replaces k_scan_reduce + k_scan_top + k_scan_chunks. 147 blocks (< 256 CUs:
// all co-resident at dispatch -> predecessor spin cannot deadlock).
// state[b]: 0 = invalid, (1<<30)|aggregate, (2<<30)|inclusive_prefix.
// Chunk sums <= NE = 1.2M < 2^30, so flag+value fit one atomic word.
// Also emits dinv[n] = rsqrt(count+1) on the fly.
__global__ __launch_bounds__(256) void k_scan(const int* __restrict__ counts,
                                              float* __restrict__ dinv,
                                              int* __restrict__ row_ptr,
                                              unsigned int* __restrict__ state) {
    __shared__ int sd[256];
    __shared__ int s_prefix;
    int t = threadIdx.x;
    int b = blockIdx.x;
    int base = b * SCAN_CHUNK + t * 4;
    int c[4];
    if (base + 3 < NN) {
        int4 v = *(const int4*)(counts + base);
        c[0] = v.x; c[1] = v.y; c[2] = v.z; c[3] = v.w;
    } else {
#pragma unroll
        for (int i = 0; i < 4; ++i) c[i] = (base + i < NN) ? counts[base + i] : 0;
    }
#pragma unroll
    for (int i = 0; i < 4; ++i)
        if (base + i < NN) dinv[base + i] = rsqrtf((float)(c[i] + 1));

    int tt = c[0] + c[1] + c[2] + c[3];
    sd[t] = tt; __syncthreads();
    for (int off = 1; off < 256; off <<= 1) {          // inclusive Hillis-Steele
        int x = (t >= off) ? sd[t - off] : 0;
        __syncthreads();
        sd[t] += x;
        __syncthreads();
    }

    if (t == 0) {
        unsigned int agg = (unsigned int)sd[255];
        if (b == 0) {
            __hip_atomic_store(&state[0], (2u << 30) | agg, __ATOMIC_RELEASE,
                               __HIP_MEMORY_SCOPE_AGENT);
            s_prefix = 0;
        } else {
            // publish own aggregate first so successors can make progress
            __hip_atomic_store(&state[b], (1u << 30) | agg, __ATOMIC_RELEASE,
                               __HIP_MEMORY_SCOPE_AGENT);
            unsigned int prefix = 0;
            int p = b - 1;
            while (true) {
                unsigned int s = __hip_atomic_load(&state[p], __ATOMIC_ACQUIRE,
                                                   __HIP_MEMORY_SCOPE_AGENT);
                unsigned int fl = s >> 30;
                if (fl == 0u) continue;                 // not published yet: spin
                prefix += s & 0x3FFFFFFFu;
                if (fl == 2u) break;                    // inclusive prefix found
                --p;                                    // aggregate: keep walking
            }
            __hip_atomic_store(&state[b], (2u << 30) | (prefix + agg),
                               __ATOMIC_RELEASE, __HIP_MEMORY_SCOPE_AGENT);
            s_prefix = (int)prefix;
        }
    }
    __syncthreads();

    int off0 = s_prefix + (sd[t] - tt);                 // exclusive offset
    int run = 0;
#pragma unroll
    for (int i = 0; i < 4; ++i) {
        if (base + i < NN) row_ptr[base + i] = off0 + run;
        run += c[i];
    }
    if (b == NBLK - 1 && t == 0) row_ptr[NN] = NE;
}

// ---------------------------------------------------------------- concat + CSR fill (fused)
// Both depend only on the scan output -> one dispatch, block-ID partitioned.
#define CONCAT_BLOCKS (NN * (HH / 4) / 256)             // 9375 (exact)
#define FILL_BLOCKS   ((NE / 8 + 255) / 256)            // 586

__global__ __launch_bounds__(256) void k_concat_fill(
    const float4* __restrict__ users, const float4* __restrict__ items,
    const float* __restrict__ dinv, __half2* __restrict__ xs, float4* __restrict__ out,
    const int4* __restrict__ src4, const int4* __restrict__ dst4,
    const int4* __restrict__ rank4, const int* __restrict__ row_ptr,
    int* __restrict__ col) {
    if (blockIdx.x < CONCAT_BLOCKS) {
        // -------- concat + prescale: xs = fp16(dinv * concat(users, items)),
        // plus fp32 passthrough outputs O1/O3.
        int i = blockIdx.x * 256 + threadIdx.x;          // over NN*16 float4
        const int UB = NU * (HH / 4);                    // 1,600,000
        float4 v;
        if (i < UB) {
            v = users[i];
            out[UB + i] = v;                             // O1 = users_emb passthrough
        } else {
            int j = i - UB;
            v = items[j];
            out[2 * UB + NI * (HH / 4) + j] = v;         // O3 = items_emb passthrough
        }
        float dv = dinv[i >> 4];                         // node = i/16
        xs[2 * i]     = __halves2half2(__float2half_rn(v.x * dv), __float2half_rn(v.y * dv));
        xs[2 * i + 1] = __halves2half2(__float2half_rn(v.z * dv), __float2half_rn(v.w * dv));
    } else {
        // -------- CSR fill: col[row_ptr[dst] + rank] = src. 8 edges/thread.
        int t = (blockIdx.x - CONCAT_BLOCKS) * 256 + threadIdx.x;   // over NE/8
        if (t >= NE / 8) return;
        int4 s0 = src4[2 * t],  s1 = src4[2 * t + 1];
        int4 d0 = dst4[2 * t],  d1 = dst4[2 * t + 1];
        int4 r0 = rank4[2 * t], r1 = rank4[2 * t + 1];
        int p0 = row_ptr[d0.x], p1 = row_ptr[d0.y], p2 = row_ptr[d0.z], p3 = row_ptr[d0.w];
        int p4 = row_ptr[d1.x], p5 = row_ptr[d1.y], p6 = row_ptr[d1.z], p7 = row_ptr[d1.w];
        col[p0 + r0.x] = s0.x;
        col[p1 + r0.y] = s0.y;
        col[p2 + r0.z] = s0.z;
        col[p3 + r0.w] = s0.w;
        col[p4 + r1.x] = s1.x;
        col[p5 + r1.y] = s1.y;
        col[p6 + r1.z] = s1.z;
        col[p7 + r1.w] = s1.w;
    }
}

// ---------------------------------------------------------------- aggregation (quad-gather)
// y[n] = fp16( dinv[n] * (xs[n] + sum_{s in N(n)} xs[s]) )
// Wave = 4 quads x 16 lanes. Each QUAD gathers a different neighbor row; a lane
// holds 4 half-features (uint2 = 8 B). One gather instruction moves 4 rows
// (512 B) vs 1 row (128 B) for lane=feature — 4x fewer memory instructions.
// 2 nodes/wave x 2 steps in flight = 16 rows outstanding. Tail slots gather the
// zeroed pad row NN. Epilogue: shfl_xor(16/32) cross-quad reduce; quads 0/1
// store the two fp16 rows in a single instruction.
__global__ __launch_bounds__(256) void k_aggregate(const __half* __restrict__ x,
                                                   __half* __restrict__ y,
                                                   const float* __restrict__ dinv,
                                                   const int* __restrict__ row_ptr,
                                                   const int* __restrict__ col) {
    int lane = threadIdx.x & 63;
    int wave = blockIdx.x * 4 + (threadIdx.x >> 6);
    int na = wave * 2;
    if (na >= NN) return;
    int nb = na + 1;                     // NN even: always valid
    int q  = lane >> 4;                  // quad 0..3 (row slot within a step)
    int f4 = (lane & 15) << 2;           // 4-feature base for this lane

    float a0 = 0.f, a1 = 0.f, a2 = 0.f, a3 = 0.f;
    float b0 = 0.f, b1 = 0.f, b2 = 0.f, b3 = 0.f;

#define GATHER(r, c0, c1, c2, c3)                                          \
    {                                                                      \
        uint2 raw = *(const uint2*)(x + (size_t)(r) * HH + f4);            \
        float2 f0 = __half22float2(*(__half2*)&raw.x);                     \
        float2 f1 = __half22float2(*(__half2*)&raw.y);                     \
        c0 += f0.x; c1 += f0.y; c2 += f1.x; c3 += f1.y;                    \
    }

    int ea = row_ptr[na], enda = row_ptr[na + 1];
    int eb = enda,        endb = row_ptr[nb + 1];   // rows adjacent

    // prologue step: quad 0 = self row, quads 1-3 = first 3 edges (pad -> NN)
    {
        int ia = ea + q - 1;
        int ib = eb + q - 1;
        int rA = (q == 0) ? na : ((ia < enda) ? col[ia] : NN);
        int rB = (q == 0) ? nb : ((ib < endb) ? col[ib] : NN);
        GATHER(rA, a0, a1, a2, a3);
        GATHER(rB, b0, b1, b2, b3);
        ea += 3; eb += 3;
    }
    // main loop: 8 edges per node per iteration (2 quad-steps each, padded)
    while (ea < enda || eb < endb) {
        int iA1 = ea + q,     iA2 = ea + 4 + q;
        int iB1 = eb + q,     iB2 = eb + 4 + q;
        int rA1 = (iA1 < enda) ? col[iA1] : NN;
        int rA2 = (iA2 < enda) ? col[iA2] : NN;
        int rB1 = (iB1 < endb) ? col[iB1] : NN;
        int rB2 = (iB2 < endb) ? col[iB2] : NN;
        GATHER(rA1, a0, a1, a2, a3);
        GATHER(rA2, a0, a1, a2, a3);
        GATHER(rB1, b0, b1, b2, b3);
        GATHER(rB2, b0, b1, b2, b3);
        ea += 8; eb += 8;
    }
#undef GATHER

    // cross-quad reduction: quads differ in lane bits 4,5
    a0 += __shfl_xor(a0, 16); a1 += __shfl_xor(a1, 16);
    a2 += __shfl_xor(a2, 16); a3 += __shfl_xor(a3, 16);
    b0 += __shfl_xor(b0, 16); b1 += __shfl_xor(b1, 16);
    b2 += __shfl_xor(b2, 16); b3 += __shfl_xor(b3, 16);
    a0 += __shfl_xor(a0, 32); a1 += __shfl_xor(a1, 32);
    a2 += __shfl_xor(a2, 32); a3 += __shfl_xor(a3, 32);
    b0 += __shfl_xor(b0, 32); b1 += __shfl_xor(b1, 32);
    b2 += __shfl_xor(b2, 32); b3 += __shfl_xor(b3, 32);

    // quads 0/1 store node a / node b rows (one 256-B store instruction)
    if (lane < 32) {
        int   n  = (q == 0) ? na : nb;
        float dv = dinv[n];
        float s0 = (q == 0) ? a0 : b0;
        float s1 = (q == 0) ? a1 : b1;
        float s2 = (q == 0) ? a2 : b2;
        float s3 = (q == 0) ? a3 : b3;
        __half2 h0 = __halves2half2(__float2half_rn(dv * s0), __float2half_rn(dv * s1));
        __half2 h1 = __halves2half2(__float2half_rn(dv * s2), __float2half_rn(dv * s3));
        uint2 packed;
        packed.x = *(unsigned int*)&h0;
        packed.y = *(unsigned int*)&h1;
        *(uint2*)(y + (size_t)n * HH + f4) = packed;
    }
}

// ---------------------------------------------------------------- GEMM: out = y @ W + b
// y is fp16 (aggregate output). 256 threads, 128 rows/block, 4x8 thread tile,
// W + y-tile (converted to fp32) in LDS.
// OutT=__half: writes NEXT layer's prescaled gather source fp16(dinv*(yW+b)).
// OutT=float:  final layer — split-write fp32 into d_out's two x slices.
#define GR 128
#define XSS 65   // +1 pad: conflict-free scalar broadcasts
template <typename OutT>
__global__ __launch_bounds__(256) void k_gemm(const __half* __restrict__ y,
                                              const float* __restrict__ W,
                                              const float* __restrict__ b,
                                              const float* __restrict__ dinv,
                                              OutT* __restrict__ out_lo,
                                              OutT* __restrict__ out_hi,
                                              int split) {
    __shared__ float xs[GR * XSS];   // 33.3 KB
    __shared__ float ws[HH * HH];    // 16 KB
    int t = threadIdx.x;
    int rowBase = blockIdx.x * GR;

    {   // stage W: 1024 float4 / 256 threads
        const float4* W4 = (const float4*)W;
        float4* ws4 = (float4*)ws;
#pragma unroll
        for (int i = 0; i < 4; ++i) ws4[i * 256 + t] = W4[i * 256 + t];
    }
    // stage y tile: 1024 8-half chunks / 256 threads, fp16 -> fp32 into LDS
#pragma unroll
    for (int it = 0; it < 4; ++it) {
        int g = it * 256 + t;        // 0..1023
        int r = g >> 3;
        int c0 = (g & 7) * 8;
        int row = rowBase + r;
        if (row < NN) {
            int4 raw = *(const int4*)(y + (size_t)row * HH + c0);   // 8 halves
            __half2 h0 = *(__half2*)&raw.x, h1 = *(__half2*)&raw.y;
            __half2 h2 = *(__half2*)&raw.z, h3 = *(__half2*)&raw.w;
            float2 f0 = __half22float2(h0), f1 = __half22float2(h1);
            float2 f2 = __half22float2(h2), f3 = __half22float2(h3);
            float* dp = xs + r * XSS + c0;
            dp[0] = f0.x; dp[1] = f0.y; dp[2] = f1.x; dp[3] = f1.y;
            dp[4] = f2.x; dp[5] = f2.y; dp[6] = f3.x; dp[7] = f3.y;
        }
    }
    __syncthreads();

    int tx = t & 7;        // 8 col-groups of 8
    int ty = t >> 3;       // 32 row-groups of 4
    int j0 = tx * 8;
    int r0 = ty * 4;

    float acc[4][8];
#pragma unroll
    for (int i = 0; i < 4; ++i)
#pragma unroll
        for (int j = 0; j < 8; ++j) acc[i][j] = 0.f;

    for (int k = 0; k < HH; ++k) {
        float4 w0 = *(const float4*)(ws + k * HH + j0);
        float4 w1 = *(const float4*)(ws + k * HH + j0 + 4);
        float wv[8] = {w0.x, w0.y, w0.z, w0.w, w1.x, w1.y, w1.z, w1.w};
#pragma unroll
        for (int i = 0; i < 4; ++i) {
            float xv = xs[(r0 + i) * XSS + k];
#pragma unroll
            for (int j = 0; j < 8; ++j) acc[i][j] += xv * wv[j];
        }
    }

    float bj[8];
#pragma unroll
    for (int j = 0; j < 8; ++j) bj[j] = b[j0 + j];

#pragma unroll
    for (int i = 0; i < 4; ++i) {
        int r = rowBase + r0 + i;
        if (r >= NN) continue;
        if constexpr (std::is_same_v<OutT, float>) {
            float4 o0 = make_float4(acc[i][0] + bj[0], acc[i][1] + bj[1],
                                    acc[i][2] + bj[2], acc[i][3] + bj[3]);
            float4 o1 = make_float4(acc[i][4] + bj[4], acc[i][5] + bj[5],
                                    acc[i][6] + bj[6], acc[i][7] + bj[7]);
            float* d = (r < split) ? ((float*)out_lo + (size_t)r * HH)
                                   : ((float*)out_hi + (size_t)(r - split) * HH);
            *(float4*)(d + j0) = o0;
            *(float4*)(d + j0 + 4) = o1;
        } else {
            float dv = dinv[r];   // prescale for next layer's gather source
            __half2 h[4];
#pragma unroll
            for (int j = 0; j < 4; ++j)
                h[j] = __halves2half2(
                    __float2half_rn((acc[i][2 * j]     + bj[2 * j])     * dv),
                    __float2half_rn((acc[i][2 * j + 1] + bj[2 * j + 1]) * dv));
            __half* d = (__half*)out_lo + (size_t)r * HH + j0;
            *(int4*)d = *(int4*)h;   // 16-B store
        }
    }
}

// ---------------------------------------------------------------- launch
extern "C" void kernel_launch(void* const* d_in, const int* in_sizes, int n_in,
                              void* d_out, int out_size, void* d_ws, size_t ws_size,
                              hipStream_t stream) {
    const int*   edge  = (const int*)d_in[0];
    const int*   src   = edge;           // edge_index[0]
    const int*   dst   = edge + NE;      // edge_index[1]
    const float* users = (const float*)d_in[1];
    const float* items = (const float*)d_in[2];
    const float* Ws    = (const float*)d_in[3];   // [3][64][64]
    const float* bs    = (const float*)d_in[4];   // [3][64]
    float*       out   = (float*)d_out;

    // workspace carve (~50 MB total). Xs0 has NN+1 rows: row NN is a zeroed pad
    // row targeted by the aggregate's tail gathers (zeroed by k_rank block 0).
    // state (lookback scan) sits directly before counts: one memset covers both.
    char* w = (char*)d_ws;
    __half* Xs0     = (__half*)w; w += (size_t)(NN + 1) * HH * 2;   // 19.2 MB
    __half* Xs1     = (__half*)w; w += (size_t)(NN + 1) * HH * 2;   // 19.2 MB
    float*  dinv    = (float*)w;  w += (size_t)NN * 4;
    unsigned int* state = (unsigned int*)w; w += 256 * 4;
    int*    counts  = (int*)w;    w += (size_t)NN * 4;
    int*    row_ptr = (int*)w;    w += (size_t)(NN + 1) * 4;
    w += 12;                                                  // realign to 16
    int*    col     = (int*)w;    w += (size_t)NE * 4;        // 4.8 MB
    int*    rank    = (int*)w;    w += (size_t)NE * 4;        // 4.8 MB
    (void)ws_size; (void)in_sizes; (void)n_in; (void)out_size;

    // zero lookback state + counts in one shot (contiguous)
    hipMemsetAsync(state, 0, (size_t)(256 + NN) * sizeof(int), stream);

    k_rank<<<(NE / 8 + 255) / 256, 256, 0, stream>>>(
        (const int4*)dst, counts, (int4*)rank, Xs0 + (size_t)NN * HH);
    k_scan<<<NBLK, 256, 0, stream>>>(counts, dinv, row_ptr, state);
    k_concat_fill<<<CONCAT_BLOCKS + FILL_BLOCKS, 256, 0, stream>>>(
        (const float4*)users, (const float4*)items, dinv, (__half2*)Xs0, (float4*)out,
        (const int4*)src, (const int4*)dst, (const int4*)rank, row_ptr, col);

    // per layer: aggregate (Xs0 -> Xs1 fp16), gemm (Xs1 -> Xs0 / final out)
    const int AGG_BLOCKS  = NN / 8;                    // 2 nodes/wave, 4 waves/block
    const int GEMM_BLOCKS = (NN + GR - 1) / GR;

    k_aggregate<<<AGG_BLOCKS, 256, 0, stream>>>(Xs0, Xs1, dinv, row_ptr, col);
    k_gemm<__half><<<GEMM_BLOCKS, 256, 0, stream>>>(
        Xs1, Ws + 0 * HH * HH, bs + 0 * HH, dinv, Xs0, Xs0, NN);
    k_aggregate<<<AGG_BLOCKS, 256, 0, stream>>>(Xs0, Xs1, dinv, row_ptr, col);
    k_gemm<__half><<<GEMM_BLOCKS, 256, 0, stream>>>(
        Xs1, Ws + 1 * HH * HH, bs + 1 * HH, dinv, Xs0, Xs0, NN);
    k_aggregate<<<AGG_BLOCKS, 256, 0, stream>>>(Xs0, Xs1, dinv, row_ptr, col);
    k_gemm<float><<<GEMM_BLOCKS, 256, 0, stream>>>(
        Xs1, Ws + 2 * HH * HH, bs + 2 * HH, dinv,
        out /* x_users */, out + (size_t)2 * NU * HH /* x_items */, NU);
}

// Round 2
// 414.480 us; speedup vs baseline: 1.0447x; 1.0447x over previous
//
#include <hip/hip_runtime.h>
#include <hip/hip_fp16.h>

#define NU 100000
#define NI 50000
#define NN 150000          // NU + NI (even)
#define HH 64
#define NE 1200000

#define SCAN_CHUNK 1024
#define NBLK ((NN + SCAN_CHUNK - 1) / SCAN_CHUNK)   // 147
#define AGG_BLOCKS (NN / 8)                          // 18750 (exact)
#define UBLK ((NN + 255) / 256)                      // 586

// ---------------------------------------------------------------- degree histogram + rank
// rank[e] = this edge's ordinal among same-dst edges (atomicAdd return value).
// 8 edges/thread keeps 8 independent atomics in flight (latency-bound op).
// Block 0 also zeroes both Xs pad rows (row NN, gathered by aggregate tails).
__global__ __launch_bounds__(256) void k_rank(const int4* __restrict__ dst4,
                                              int* __restrict__ counts,
                                              int4* __restrict__ rank4,
                                              __half* __restrict__ pad0,
                                              __half* __restrict__ pad1) {
    if (blockIdx.x == 0 && threadIdx.x < 16) {
        if (threadIdx.x < 8) ((int4*)pad0)[threadIdx.x] = make_int4(0, 0, 0, 0);
        else                 ((int4*)pad1)[threadIdx.x - 8] = make_int4(0, 0, 0, 0);
    }
    int t = blockIdx.x * blockDim.x + threadIdx.x;   // over NE/8
    if (t >= NE / 8) return;
    int4 d0 = dst4[2 * t], d1 = dst4[2 * t + 1];
    int4 r0, r1;
    r0.x = atomicAdd(&counts[d0.x], 1);
    r0.y = atomicAdd(&counts[d0.y], 1);
    r0.z = atomicAdd(&counts[d0.z], 1);
    r0.w = atomicAdd(&counts[d0.w], 1);
    r1.x = atomicAdd(&counts[d1.x], 1);
    r1.y = atomicAdd(&counts[d1.y], 1);
    r1.z = atomicAdd(&counts[d1.z], 1);
    r1.w = atomicAdd(&counts[d1.w], 1);
    rank4[2 * t]     = r0;
    rank4[2 * t + 1] = r1;
}

// ---------------------------------------------------------------- single-pass scan (decoupled lookback)
// 147 blocks (< 256 CUs: all co-resident at dispatch -> spin cannot deadlock).
// state[b]: 0 = invalid, (1<<30)|aggregate, (2<<30)|inclusive_prefix.
// Also emits dinv[n] = rsqrt(deg+1) and dinv2[n] = 1/(deg+1) (exact d^2).
__global__ __launch_bounds__(256) void k_scan(const int* __restrict__ counts,
                                              float* __restrict__ dinv,
                                              float* __restrict__ dinv2,
                                              int* __restrict__ row_ptr,
                                              unsigned int* __restrict__ state) {
    __shared__ int sd[256];
    __shared__ int s_prefix;
    int t = threadIdx.x;
    int b = blockIdx.x;
    int base = b * SCAN_CHUNK + t * 4;
    int c[4];
    if (base + 3 < NN) {
        int4 v = *(const int4*)(counts + base);
        c[0] = v.x; c[1] = v.y; c[2] = v.z; c[3] = v.w;
    } else {
#pragma unroll
        for (int i = 0; i < 4; ++i) c[i] = (base + i < NN) ? counts[base + i] : 0;
    }
#pragma unroll
    for (int i = 0; i < 4; ++i)
        if (base + i < NN) {
            dinv[base + i]  = rsqrtf((float)(c[i] + 1));
            dinv2[base + i] = 1.0f / (float)(c[i] + 1);
        }

    int tt = c[0] + c[1] + c[2] + c[3];
    sd[t] = tt; __syncthreads();
    for (int off = 1; off < 256; off <<= 1) {          // inclusive Hillis-Steele
        int x = (t >= off) ? sd[t - off] : 0;
        __syncthreads();
        sd[t] += x;
        __syncthreads();
    }

    if (t == 0) {
        unsigned int agg = (unsigned int)sd[255];
        if (b == 0) {
            __hip_atomic_store(&state[0], (2u << 30) | agg, __ATOMIC_RELEASE,
                               __HIP_MEMORY_SCOPE_AGENT);
            s_prefix = 0;
        } else {
            __hip_atomic_store(&state[b], (1u << 30) | agg, __ATOMIC_RELEASE,
                               __HIP_MEMORY_SCOPE_AGENT);
            unsigned int prefix = 0;
            int p = b - 1;
            while (true) {
                unsigned int s = __hip_atomic_load(&state[p], __ATOMIC_ACQUIRE,
                                                   __HIP_MEMORY_SCOPE_AGENT);
                unsigned int fl = s >> 30;
                if (fl == 0u) { __builtin_amdgcn_s_sleep(1); continue; }
                prefix += s & 0x3FFFFFFFu;
                if (fl == 2u) break;
                --p;
            }
            __hip_atomic_store(&state[b], (2u << 30) | (prefix + agg),
                               __ATOMIC_RELEASE, __HIP_MEMORY_SCOPE_AGENT);
            s_prefix = (int)prefix;
        }
    }
    __syncthreads();

    int off0 = s_prefix + (sd[t] - tt);                 // exclusive offset
    int run = 0;
#pragma unroll
    for (int i = 0; i < 4; ++i) {
        if (base + i < NN) row_ptr[base + i] = off0 + run;
        run += c[i];
    }
    if (b == NBLK - 1 && t == 0) row_ptr[NN] = NE;
}

// ---------------------------------------------------------------- concat + CSR fill (fused)
#define CONCAT_BLOCKS (NN * (HH / 4) / 256)             // 9375 (exact)
#define FILL_BLOCKS   ((NE / 8 + 255) / 256)            // 586

__global__ __launch_bounds__(256) void k_concat_fill(
    const float4* __restrict__ users, const float4* __restrict__ items,
    const float* __restrict__ dinv, __half2* __restrict__ xs, float4* __restrict__ out,
    const int4* __restrict__ src4, const int4* __restrict__ dst4,
    const int4* __restrict__ rank4, const int* __restrict__ row_ptr,
    int* __restrict__ col) {
    if (blockIdx.x < CONCAT_BLOCKS) {
        // xs = fp16(dinv * concat(users, items)), plus fp32 passthrough outputs.
        int i = blockIdx.x * 256 + threadIdx.x;          // over NN*16 float4
        const int UB = NU * (HH / 4);                    // 1,600,000
        float4 v;
        if (i < UB) {
            v = users[i];
            out[UB + i] = v;                             // O1 = users_emb passthrough
        } else {
            int j = i - UB;
            v = items[j];
            out[2 * UB + NI * (HH / 4) + j] = v;         // O3 = items_emb passthrough
        }
        float dv = dinv[i >> 4];                         // node = i/16
        xs[2 * i]     = __halves2half2(__float2half_rn(v.x * dv), __float2half_rn(v.y * dv));
        xs[2 * i + 1] = __halves2half2(__float2half_rn(v.z * dv), __float2half_rn(v.w * dv));
    } else {
        // CSR fill: col[row_ptr[dst] + rank] = src. 8 edges/thread.
        int t = (blockIdx.x - CONCAT_BLOCKS) * 256 + threadIdx.x;   // over NE/8
        if (t >= NE / 8) return;
        int4 s0 = src4[2 * t],  s1 = src4[2 * t + 1];
        int4 d0 = dst4[2 * t],  d1 = dst4[2 * t + 1];
        int4 r0 = rank4[2 * t], r1 = rank4[2 * t + 1];
        int p0 = row_ptr[d0.x], p1 = row_ptr[d0.y], p2 = row_ptr[d0.z], p3 = row_ptr[d0.w];
        int p4 = row_ptr[d1.x], p5 = row_ptr[d1.y], p6 = row_ptr[d1.z], p7 = row_ptr[d1.w];
        col[p0 + r0.x] = s0.x;
        col[p1 + r0.y] = s0.y;
        col[p2 + r0.z] = s0.z;
        col[p3 + r0.w] = s0.w;
        col[p4 + r1.x] = s1.x;
        col[p5 + r1.y] = s1.y;
        col[p6 + r1.z] = s1.z;
        col[p7 + r1.w] = s1.w;
    }
}

// ---------------------------------------------------------------- aggregation (quad-gather)
// y[n] = fp16( scale[n] * (xs[n] + sum_{s in N(n)} xs[s]) )
// scale = dinv2 for intermediate passes (output stays prescaled for the next
// gather), dinv for the final pass (true A^3 x0, fed to the single gemm).
// MODE 1: prefix blocks compute u1 = A.1 (and prescaled p1u) + one block
//         combines Ws (What = W0 W1 W2, c0 = b0^T W1 W2, c1 = b1^T W2).
// MODE 2: prefix blocks compute u2 = A u1.
// MODE 0: plain aggregate.
template <int MODE>
__global__ __launch_bounds__(256) void k_aggregate(
    const __half* __restrict__ x, __half* __restrict__ y,
    const float* __restrict__ scale,
    const int* __restrict__ row_ptr, const int* __restrict__ col,
    const float* __restrict__ dinv, const float* __restrict__ pin,
    float* __restrict__ uout, float* __restrict__ pout,
    const float* __restrict__ Wfull, const float* __restrict__ bfull,
    float* __restrict__ What, float* __restrict__ cvec) {
    int bid = blockIdx.x;
    if (MODE != 0) {
        const int EXTRA = (MODE == 1) ? (UBLK + 1) : UBLK;
        if (bid < EXTRA) {
            if (MODE == 1 && bid == UBLK) {
                // ---- W-combine (one block; 16 KB LDS, no occupancy impact) ----
                __shared__ float W12[HH * HH];
                int t = threadIdx.x;
                int r = t >> 2, j0 = (t & 3) * 16;
                const float* W0 = Wfull;
                const float* W1 = Wfull + HH * HH;
                const float* W2 = Wfull + 2 * HH * HH;
                float acc[16];
#pragma unroll
                for (int j = 0; j < 16; ++j) acc[j] = 0.f;
                for (int k = 0; k < HH; ++k) {
                    float a = W1[r * HH + k];
                    const float* bp = W2 + k * HH + j0;
#pragma unroll
                    for (int j = 0; j < 16; ++j) acc[j] += a * bp[j];
                }
#pragma unroll
                for (int j = 0; j < 16; ++j) W12[r * HH + j0 + j] = acc[j];
                if (t < HH) {                       // c1 = b1^T W2
                    float s = 0.f;
                    for (int k = 0; k < HH; ++k) s += bfull[HH + k] * W2[k * HH + t];
                    cvec[HH + t] = s;
                }
                __syncthreads();
#pragma unroll
                for (int j = 0; j < 16; ++j) acc[j] = 0.f;
                for (int k = 0; k < HH; ++k) {      // What = W0 * W12
                    float a = W0[r * HH + k];
                    const float* bp = W12 + k * HH + j0;
#pragma unroll
                    for (int j = 0; j < 16; ++j) acc[j] += a * bp[j];
                }
#pragma unroll
                for (int j = 0; j < 16; ++j) What[r * HH + j0 + j] = acc[j];
                if (t < HH) {                       // c0 = b0^T W12
                    float s = 0.f;
                    for (int k = 0; k < HH; ++k) s += bfull[k] * W12[k * HH + t];
                    cvec[t] = s;
                }
                return;
            }
            // ---- scalar u-pass: u = dinv .* (pin_self + sum_nbr pin) ----
            int n = bid * 256 + threadIdx.x;
            if (n < NN) {
                float dv = dinv[n];
                float acc = pin[n];
                int e1 = row_ptr[n + 1];
                for (int e = row_ptr[n]; e < e1; ++e) acc += pin[col[e]];
                float u = dv * acc;
                uout[n] = u;
                if (MODE == 1) pout[n] = dv * u;    // prescaled for the next A
            }
            return;
        }
        bid -= EXTRA;
    }

    // ---- main aggregate: wave = 4 quads x 16 lanes, 2 nodes/wave ----
    int lane = threadIdx.x & 63;
    int wave = bid * 4 + (threadIdx.x >> 6);
    int na = wave * 2;
    if (na >= NN) return;
    int nb = na + 1;                     // NN even: always valid
    int q  = lane >> 4;                  // quad 0..3 (row slot within a step)
    int f4 = (lane & 15) << 2;           // 4-feature base for this lane

    float a0 = 0.f, a1 = 0.f, a2 = 0.f, a3 = 0.f;
    float b0 = 0.f, b1 = 0.f, b2 = 0.f, b3 = 0.f;

#define GATHER(r, c0, c1, c2, c3)                                          \
    {                                                                      \
        uint2 raw = *(const uint2*)(x + (size_t)(r) * HH + f4);            \
        float2 f0 = __half22float2(*(__half2*)&raw.x);                     \
        float2 f1 = __half22float2(*(__half2*)&raw.y);                     \
        c0 += f0.x; c1 += f0.y; c2 += f1.x; c3 += f1.y;                    \
    }

    int ea = row_ptr[na], enda = row_ptr[na + 1];
    int eb = enda,        endb = row_ptr[nb + 1];   // rows adjacent

    // prologue: quad 0 = self row, quads 1-3 = first 3 edges (pad -> NN)
    {
        int ia = ea + q - 1;
        int ib = eb + q - 1;
        int rA = (q == 0) ? na : ((ia < enda) ? col[ia] : NN);
        int rB = (q == 0) ? nb : ((ib < endb) ? col[ib] : NN);
        GATHER(rA, a0, a1, a2, a3);
        GATHER(rB, b0, b1, b2, b3);
        ea += 3; eb += 3;
    }
    while (ea < enda || eb < endb) {
        int iA1 = ea + q,     iA2 = ea + 4 + q;
        int iB1 = eb + q,     iB2 = eb + 4 + q;
        int rA1 = (iA1 < enda) ? col[iA1] : NN;
        int rA2 = (iA2 < enda) ? col[iA2] : NN;
        int rB1 = (iB1 < endb) ? col[iB1] : NN;
        int rB2 = (iB2 < endb) ? col[iB2] : NN;
        GATHER(rA1, a0, a1, a2, a3);
        GATHER(rA2, a0, a1, a2, a3);
        GATHER(rB1, b0, b1, b2, b3);
        GATHER(rB2, b0, b1, b2, b3);
        ea += 8; eb += 8;
    }
#undef GATHER

    // cross-quad reduction: quads differ in lane bits 4,5
    a0 += __shfl_xor(a0, 16); a1 += __shfl_xor(a1, 16);
    a2 += __shfl_xor(a2, 16); a3 += __shfl_xor(a3, 16);
    b0 += __shfl_xor(b0, 16); b1 += __shfl_xor(b1, 16);
    b2 += __shfl_xor(b2, 16); b3 += __shfl_xor(b3, 16);
    a0 += __shfl_xor(a0, 32); a1 += __shfl_xor(a1, 32);
    a2 += __shfl_xor(a2, 32); a3 += __shfl_xor(a3, 32);
    b0 += __shfl_xor(b0, 32); b1 += __shfl_xor(b1, 32);
    b2 += __shfl_xor(b2, 32); b3 += __shfl_xor(b3, 32);

    if (lane < 32) {
        int   n  = (q == 0) ? na : nb;
        float dv = scale[n];
        float s0 = (q == 0) ? a0 : b0;
        float s1 = (q == 0) ? a1 : b1;
        float s2 = (q == 0) ? a2 : b2;
        float s3 = (q == 0) ? a3 : b3;
        __half2 h0 = __halves2half2(__float2half_rn(dv * s0), __float2half_rn(dv * s1));
        __half2 h1 = __halves2half2(__float2half_rn(dv * s2), __float2half_rn(dv * s3));
        uint2 packed;
        packed.x = *(unsigned int*)&h0;
        packed.y = *(unsigned int*)&h1;
        *(uint2*)(y + (size_t)n * HH + f4) = packed;
    }
}

// ---------------------------------------------------------------- final GEMM
// out = (A^3 x0) @ What + u2 c0^T + u1 c1^T + 1 b2^T, split fp32 write.
#define GR 128
#define XSS 65   // +1 pad: conflict-free scalar broadcasts
__global__ __launch_bounds__(256) void k_gemm_final(
    const __half* __restrict__ y, const float* __restrict__ W,
    const float* __restrict__ b2, const float* __restrict__ cvec,
    const float* __restrict__ u1, const float* __restrict__ u2,
    float* __restrict__ out_lo, float* __restrict__ out_hi) {
    __shared__ float xs[GR * XSS];   // 33.3 KB
    __shared__ float ws[HH * HH];    // 16 KB
    int t = threadIdx.x;
    int rowBase = blockIdx.x * GR;

    {   // stage W: 1024 float4 / 256 threads
        const float4* W4 = (const float4*)W;
        float4* ws4 = (float4*)ws;
#pragma unroll
        for (int i = 0; i < 4; ++i) ws4[i * 256 + t] = W4[i * 256 + t];
    }
#pragma unroll
    for (int it = 0; it < 4; ++it) {
        int g = it * 256 + t;        // 0..1023
        int r = g >> 3;
        int c0 = (g & 7) * 8;
        int row = rowBase + r;
        if (row < NN) {
            int4 raw = *(const int4*)(y + (size_t)row * HH + c0);   // 8 halves
            __half2 h0 = *(__half2*)&raw.x, h1 = *(__half2*)&raw.y;
            __half2 h2 = *(__half2*)&raw.z, h3 = *(__half2*)&raw.w;
            float2 f0 = __half22float2(h0), f1 = __half22float2(h1);
            float2 f2 = __half22float2(h2), f3 = __half22float2(h3);
            float* dp = xs + r * XSS + c0;
            dp[0] = f0.x; dp[1] = f0.y; dp[2] = f1.x; dp[3] = f1.y;
            dp[4] = f2.x; dp[5] = f2.y; dp[6] = f3.x; dp[7] = f3.y;
        }
    }
    __syncthreads();

    int tx = t & 7;        // 8 col-groups of 8
    int ty = t >> 3;       // 32 row-groups of 4
    int j0 = tx * 8;
    int r0 = ty * 4;

    float acc[4][8];
#pragma unroll
    for (int i = 0; i < 4; ++i)
#pragma unroll
        for (int j = 0; j < 8; ++j) acc[i][j] = 0.f;

    for (int k = 0; k < HH; ++k) {
        float4 w0 = *(const float4*)(ws + k * HH + j0);
        float4 w1 = *(const float4*)(ws + k * HH + j0 + 4);
        float wv[8] = {w0.x, w0.y, w0.z, w0.w, w1.x, w1.y, w1.z, w1.w};
#pragma unroll
        for (int i = 0; i < 4; ++i) {
            float xv = xs[(r0 + i) * XSS + k];
#pragma unroll
            for (int j = 0; j < 8; ++j) acc[i][j] += xv * wv[j];
        }
    }

    float c0j[8], c1j[8], b2j[8];
#pragma unroll
    for (int j = 0; j < 8; ++j) {
        c0j[j] = cvec[j0 + j];
        c1j[j] = cvec[HH + j0 + j];
        b2j[j] = b2[j0 + j];
    }

#pragma unroll
    for (int i = 0; i < 4; ++i) {
        int r = rowBase + r0 + i;
        if (r >= NN) continue;
        float u2r = u2[r], u1r = u1[r];
        float base[8];
#pragma unroll
        for (int j = 0; j < 8; ++j) base[j] = u2r * c0j[j] + u1r * c1j[j] + b2j[j];
        float4 o0 = make_float4(acc[i][0] + base[0], acc[i][1] + base[1],
                                acc[i][2] + base[2], acc[i][3] + base[3]);
        float4 o1 = make_float4(acc[i][4] + base[4], acc[i][5] + base[5],
                                acc[i][6] + base[6], acc[i][7] + base[7]);
        float* d = (r < NU) ? (out_lo + (size_t)r * HH)
                            : (out_hi + (size_t)(r - NU) * HH);
        *(float4*)(d + j0) = o0;
        *(float4*)(d + j0 + 4) = o1;
    }
}

// ---------------------------------------------------------------- launch
extern "C" void kernel_launch(void* const* d_in, const int* in_sizes, int n_in,
                              void* d_out, int out_size, void* d_ws, size_t ws_size,
                              hipStream_t stream) {
    const int*   edge  = (const int*)d_in[0];
    const int*   src   = edge;           // edge_index[0]
    const int*   dst   = edge + NE;      // edge_index[1]
    const float* users = (const float*)d_in[1];
    const float* items = (const float*)d_in[2];
    const float* Ws    = (const float*)d_in[3];   // [3][64][64]
    const float* bs    = (const float*)d_in[4];   // [3][64]
    float*       out   = (float*)d_out;

    // workspace carve (~52 MB). Xs row NN is a zeroed pad row (k_rank block 0).
    // state (lookback scan) sits directly before counts: one memset covers both.
    char* w = (char*)d_ws;
    __half* Xs0     = (__half*)w; w += (size_t)(NN + 1) * HH * 2;   // 19.2 MB
    __half* Xs1     = (__half*)w; w += (size_t)(NN + 1) * HH * 2;   // 19.2 MB
    float*  dinv    = (float*)w;  w += (size_t)NN * 4;
    float*  dinv2   = (float*)w;  w += (size_t)NN * 4;
    float*  u1      = (float*)w;  w += (size_t)NN * 4;
    float*  p1u     = (float*)w;  w += (size_t)NN * 4;
    float*  u2      = (float*)w;  w += (size_t)NN * 4;
    float*  What    = (float*)w;  w += (size_t)HH * HH * 4;         // 16 KB
    float*  cvec    = (float*)w;  w += (size_t)2 * HH * 4;          // c0, c1
    unsigned int* state = (unsigned int*)w; w += 256 * 4;
    int*    counts  = (int*)w;    w += (size_t)NN * 4;
    int*    row_ptr = (int*)w;    w += (size_t)(NN + 1) * 4;
    w += 12;                                                  // realign to 16
    int*    col     = (int*)w;    w += (size_t)NE * 4;        // 4.8 MB
    int*    rank    = (int*)w;    w += (size_t)NE * 4;        // 4.8 MB
    (void)ws_size; (void)in_sizes; (void)n_in; (void)out_size;

    hipMemsetAsync(state, 0, (size_t)(256 + NN) * sizeof(int), stream);

    k_rank<<<(NE / 8 + 255) / 256, 256, 0, stream>>>(
        (const int4*)dst, counts, (int4*)rank,
        Xs0 + (size_t)NN * HH, Xs1 + (size_t)NN * HH);
    k_scan<<<NBLK, 256, 0, stream>>>(counts, dinv, dinv2, row_ptr, state);
    k_concat_fill<<<CONCAT_BLOCKS + FILL_BLOCKS, 256, 0, stream>>>(
        (const float4*)users, (const float4*)items, dinv, (__half2*)Xs0, (float4*)out,
        (const int4*)src, (const int4*)dst, (const int4*)rank, row_ptr, col);

    // A^3 chain (3 aggregates, prefix-fused u/wcomb) + single final gemm
    k_aggregate<1><<<UBLK + 1 + AGG_BLOCKS, 256, 0, stream>>>(
        Xs0, Xs1, dinv2, row_ptr, col, dinv, dinv, u1, p1u, Ws, bs, What, cvec);
    k_aggregate<2><<<UBLK + AGG_BLOCKS, 256, 0, stream>>>(
        Xs1, Xs0, dinv2, row_ptr, col, dinv, p1u, u2, nullptr, nullptr, nullptr,
        nullptr, nullptr);
    k_aggregate<0><<<AGG_BLOCKS, 256, 0, stream>>>(
        Xs0, Xs1, dinv, row_ptr, col, nullptr, nullptr, nullptr, nullptr, nullptr,
        nullptr, nullptr, nullptr);

    const int GEMM_BLOCKS = (NN + GR - 1) / GR;
    k_gemm_final<<<GEMM_BLOCKS, 256, 0, stream>>>(
        Xs1, What, bs + 2 * HH, cvec, u1, u2,
        out /* x_users */, out + (size_t)2 * NU * HH /* x_items */);
}

// Round 3
// 403.898 us; speedup vs baseline: 1.0721x; 1.0262x over previous
//
#include <hip/hip_runtime.h>
#include <hip/hip_fp16.h>

#define NU 100000
#define NI 50000
#define NN 150000          // NU + NI (even)
#define HH 64
#define NE 1200000

#define SCAN_CHUNK 1024
#define NBLK ((NN + SCAN_CHUNK - 1) / SCAN_CHUNK)   // 147
#define AGG_BLOCKS (NN / 8)                          // 18750 (8 nodes/block)

// ---------------------------------------------------------------- degree histogram + rank
// rank[e] = this edge's ordinal among same-dst edges (atomicAdd return value).
// 8 edges/thread keeps 8 independent atomics in flight (latency-bound op).
// Block 0 also zeroes the gather pad entries: Xs0/Xs1 row NN, dinv[NN], p1u[NN].
__global__ __launch_bounds__(256) void k_rank(const int4* __restrict__ dst4,
                                              int* __restrict__ counts,
                                              int4* __restrict__ rank4,
                                              __half* __restrict__ pad0,
                                              __half* __restrict__ pad1,
                                              float* __restrict__ dinv,
                                              float* __restrict__ p1u) {
    if (blockIdx.x == 0 && threadIdx.x < 18) {
        if (threadIdx.x < 8)       ((int4*)pad0)[threadIdx.x] = make_int4(0, 0, 0, 0);
        else if (threadIdx.x < 16) ((int4*)pad1)[threadIdx.x - 8] = make_int4(0, 0, 0, 0);
        else if (threadIdx.x == 16) dinv[NN] = 0.f;
        else                        p1u[NN] = 0.f;
    }
    int t = blockIdx.x * blockDim.x + threadIdx.x;   // over NE/8
    if (t >= NE / 8) return;
    int4 d0 = dst4[2 * t], d1 = dst4[2 * t + 1];
    int4 r0, r1;
    r0.x = atomicAdd(&counts[d0.x], 1);
    r0.y = atomicAdd(&counts[d0.y], 1);
    r0.z = atomicAdd(&counts[d0.z], 1);
    r0.w = atomicAdd(&counts[d0.w], 1);
    r1.x = atomicAdd(&counts[d1.x], 1);
    r1.y = atomicAdd(&counts[d1.y], 1);
    r1.z = atomicAdd(&counts[d1.z], 1);
    r1.w = atomicAdd(&counts[d1.w], 1);
    rank4[2 * t]     = r0;
    rank4[2 * t + 1] = r1;
}

// ---------------------------------------------------------------- single-pass scan (decoupled lookback)
// 147 scan blocks + 1 W-combine block (148 < 256 CUs: co-resident, spin safe).
// state[b]: 0 = invalid, (1<<30)|aggregate, (2<<30)|inclusive_prefix.
// Emits dinv[n] = rsqrt(deg+1), dinv2[n] = 1/(deg+1).
// Block NBLK instead computes What = W0 W1 W2, c0 = b0^T W1 W2, c1 = b1^T W2.
__global__ __launch_bounds__(256) void k_scan(const int* __restrict__ counts,
                                              float* __restrict__ dinv,
                                              float* __restrict__ dinv2,
                                              int* __restrict__ row_ptr,
                                              unsigned int* __restrict__ state,
                                              const float* __restrict__ Wfull,
                                              const float* __restrict__ bfull,
                                              float* __restrict__ What,
                                              float* __restrict__ cvec) {
    __shared__ float smem[HH * HH];   // W12 for the combine block; 256 ints for scan
    __shared__ int s_prefix;
    int t = threadIdx.x;
    int b = blockIdx.x;

    if (b == NBLK) {
        // ---- W-combine (one block) ----
        int r = t >> 2, j0 = (t & 3) * 16;
        const float* W0 = Wfull;
        const float* W1 = Wfull + HH * HH;
        const float* W2 = Wfull + 2 * HH * HH;
        float acc[16];
#pragma unroll
        for (int j = 0; j < 16; ++j) acc[j] = 0.f;
        for (int k = 0; k < HH; ++k) {
            float a = W1[r * HH + k];
            const float* bp = W2 + k * HH + j0;
#pragma unroll
            for (int j = 0; j < 16; ++j) acc[j] += a * bp[j];
        }
#pragma unroll
        for (int j = 0; j < 16; ++j) smem[r * HH + j0 + j] = acc[j];   // W12 = W1*W2
        if (t < HH) {                       // c1 = b1^T W2
            float s = 0.f;
            for (int k = 0; k < HH; ++k) s += bfull[HH + k] * W2[k * HH + t];
            cvec[HH + t] = s;
        }
        __syncthreads();
#pragma unroll
        for (int j = 0; j < 16; ++j) acc[j] = 0.f;
        for (int k = 0; k < HH; ++k) {      // What = W0 * W12
            float a = W0[r * HH + k];
            const float* bp = smem + k * HH + j0;
#pragma unroll
            for (int j = 0; j < 16; ++j) acc[j] += a * bp[j];
        }
#pragma unroll
        for (int j = 0; j < 16; ++j) What[r * HH + j0 + j] = acc[j];
        if (t < HH) {                       // c0 = b0^T W12
            float s = 0.f;
            for (int k = 0; k < HH; ++k) s += bfull[k] * smem[k * HH + t];
            cvec[t] = s;
        }
        return;
    }

    int* sd = (int*)smem;
    int base = b * SCAN_CHUNK + t * 4;
    int c[4];
    if (base + 3 < NN) {
        int4 v = *(const int4*)(counts + base);
        c[0] = v.x; c[1] = v.y; c[2] = v.z; c[3] = v.w;
    } else {
#pragma unroll
        for (int i = 0; i < 4; ++i) c[i] = (base + i < NN) ? counts[base + i] : 0;
    }
#pragma unroll
    for (int i = 0; i < 4; ++i)
        if (base + i < NN) {
            dinv[base + i]  = rsqrtf((float)(c[i] + 1));
            dinv2[base + i] = 1.0f / (float)(c[i] + 1);
        }

    int tt = c[0] + c[1] + c[2] + c[3];
    sd[t] = tt; __syncthreads();
    for (int off = 1; off < 256; off <<= 1) {          // inclusive Hillis-Steele
        int x = (t >= off) ? sd[t - off] : 0;
        __syncthreads();
        sd[t] += x;
        __syncthreads();
    }

    if (t == 0) {
        unsigned int agg = (unsigned int)sd[255];
        if (b == 0) {
            __hip_atomic_store(&state[0], (2u << 30) | agg, __ATOMIC_RELEASE,
                               __HIP_MEMORY_SCOPE_AGENT);
            s_prefix = 0;
        } else {
            __hip_atomic_store(&state[b], (1u << 30) | agg, __ATOMIC_RELEASE,
                               __HIP_MEMORY_SCOPE_AGENT);
            unsigned int prefix = 0;
            int p = b - 1;
            while (true) {
                unsigned int s = __hip_atomic_load(&state[p], __ATOMIC_ACQUIRE,
                                                   __HIP_MEMORY_SCOPE_AGENT);
                unsigned int fl = s >> 30;
                if (fl == 0u) { __builtin_amdgcn_s_sleep(1); continue; }
                prefix += s & 0x3FFFFFFFu;
                if (fl == 2u) break;
                --p;
            }
            __hip_atomic_store(&state[b], (2u << 30) | (prefix + agg),
                               __ATOMIC_RELEASE, __HIP_MEMORY_SCOPE_AGENT);
            s_prefix = (int)prefix;
        }
    }
    __syncthreads();

    int off0 = s_prefix + (sd[t] - tt);                 // exclusive offset
    int run = 0;
#pragma unroll
    for (int i = 0; i < 4; ++i) {
        if (base + i < NN) row_ptr[base + i] = off0 + run;
        run += c[i];
    }
    if (b == NBLK - 1 && t == 0) row_ptr[NN] = NE;
}

// ---------------------------------------------------------------- concat + CSR fill (fused)
#define CONCAT_BLOCKS ((NN * 8 + 255) / 256)            // 4688 (thread = 8 features)
#define FILL_BLOCKS   ((NE / 8 + 255) / 256)            // 586

__global__ __launch_bounds__(256) void k_concat_fill(
    const float4* __restrict__ users, const float4* __restrict__ items,
    const float* __restrict__ dinv, int4* __restrict__ xs4, float4* __restrict__ out,
    const int4* __restrict__ src4, const int4* __restrict__ dst4,
    const int4* __restrict__ rank4, const int* __restrict__ row_ptr,
    int* __restrict__ col) {
    if (blockIdx.x < CONCAT_BLOCKS) {
        // xs = fp16(dinv * concat(users, items)) in one 16-B store per thread,
        // plus fp32 passthrough outputs O1/O3.
        int i = blockIdx.x * 256 + threadIdx.x;          // over NN*8 chunks of 8 feats
        if (i >= NN * 8) return;
        const int UB8 = NU * 8;
        const int UB4 = NU * 16;                         // user float4 count
        float4 v0, v1;
        if (i < UB8) {
            v0 = users[2 * i];
            v1 = users[2 * i + 1];
            out[UB4 + 2 * i]     = v0;                   // O1 = users_emb passthrough
            out[UB4 + 2 * i + 1] = v1;
        } else {
            int j = i - UB8;
            v0 = items[2 * j];
            v1 = items[2 * j + 1];
            out[2 * UB4 + NI * 16 + 2 * j]     = v0;     // O3 = items_emb passthrough
            out[2 * UB4 + NI * 16 + 2 * j + 1] = v1;
        }
        float dv = dinv[i >> 3];                         // node = i/8
        __half2 h[4];
        h[0] = __halves2half2(__float2half_rn(v0.x * dv), __float2half_rn(v0.y * dv));
        h[1] = __halves2half2(__float2half_rn(v0.z * dv), __float2half_rn(v0.w * dv));
        h[2] = __halves2half2(__float2half_rn(v1.x * dv), __float2half_rn(v1.y * dv));
        h[3] = __halves2half2(__float2half_rn(v1.z * dv), __float2half_rn(v1.w * dv));
        xs4[i] = *(int4*)h;
    } else {
        // CSR fill: col[row_ptr[dst] + rank] = src. 8 edges/thread.
        int t = (blockIdx.x - CONCAT_BLOCKS) * 256 + threadIdx.x;   // over NE/8
        if (t >= NE / 8) return;
        int4 s0 = src4[2 * t],  s1 = src4[2 * t + 1];
        int4 d0 = dst4[2 * t],  d1 = dst4[2 * t + 1];
        int4 r0 = rank4[2 * t], r1 = rank4[2 * t + 1];
        int p0 = row_ptr[d0.x], p1 = row_ptr[d0.y], p2 = row_ptr[d0.z], p3 = row_ptr[d0.w];
        int p4 = row_ptr[d1.x], p5 = row_ptr[d1.y], p6 = row_ptr[d1.z], p7 = row_ptr[d1.w];
        col[p0 + r0.x] = s0.x;
        col[p1 + r0.y] = s0.y;
        col[p2 + r0.z] = s0.z;
        col[p3 + r0.w] = s0.w;
        col[p4 + r1.x] = s1.x;
        col[p5 + r1.y] = s1.y;
        col[p6 + r1.z] = s1.z;
        col[p7 + r1.w] = s1.w;
    }
}

// ---------------------------------------------------------------- aggregation (octet-gather)
// y[n] = fp16( scale[n] * (xs[n] + sum_{s in N(n)} xs[s]) )
// Wave = 8 octets x 8 lanes, 2 nodes/wave. Each OCTET gathers a different row;
// a lane holds 8 half-features (int4 = 16 B). One gather instruction moves
// 8 rows (1 KB) — 2x fewer instructions than the quad version at the same MLP.
// Prologue covers self + 7 edges (avg degree = 8 -> most nodes finish there).
// UMODE!=0 additionally folds the scalar u-sum (u = dinv .* A_hat pin) into the
// SAME loop: each octet's lanes broadcast-load pin[row] (4 B, L2-hot); the
// cross-lane reduce over-counts by 8x, fixed by *0.125. UMODE==1 also writes
// pout = dinv*u (prescaled operand for the next u-pass).
template <int UMODE>
__global__ __launch_bounds__(256) void k_aggregate(
    const __half* __restrict__ x, __half* __restrict__ y,
    const float* __restrict__ scale,
    const int* __restrict__ row_ptr, const int* __restrict__ col,
    const float* __restrict__ dinv, const float* __restrict__ pin,
    float* __restrict__ uout, float* __restrict__ pout) {
    int lane = threadIdx.x & 63;
    int wave = blockIdx.x * 4 + (threadIdx.x >> 6);
    int na = wave * 2;
    if (na >= NN) return;
    int nb = na + 1;                     // NN even: always valid
    int o  = lane >> 3;                  // octet 0..7 (row slot within a step)
    int f8 = (lane & 7) << 3;            // 8-feature base for this lane

    float a[8], b[8];
#pragma unroll
    for (int j = 0; j < 8; ++j) { a[j] = 0.f; b[j] = 0.f; }
    float ua = 0.f, ub = 0.f;

#define GATHER(r, acc, uacc)                                               \
    {                                                                      \
        int4 raw = *(const int4*)(x + (size_t)(r) * HH + f8);              \
        if (UMODE) uacc += pin[r];                                         \
        __half2* hp = (__half2*)&raw;                                      \
        _Pragma("unroll")                                                  \
        for (int j = 0; j < 4; ++j) {                                      \
            float2 f = __half22float2(hp[j]);                              \
            acc[2 * j] += f.x; acc[2 * j + 1] += f.y;                      \
        }                                                                  \
    }

    int ea = row_ptr[na], enda = row_ptr[na + 1];
    int eb = enda,        endb = row_ptr[nb + 1];   // rows adjacent

    // prologue: octet 0 = self row, octets 1-7 = first 7 edges (pad -> NN)
    {
        int ia = ea + o - 1;
        int ib = eb + o - 1;
        int rA = (o == 0) ? na : ((ia < enda) ? col[ia] : NN);
        int rB = (o == 0) ? nb : ((ib < endb) ? col[ib] : NN);
        GATHER(rA, a, ua);
        GATHER(rB, b, ub);
        ea += 7; eb += 7;
    }
    while (ea < enda || eb < endb) {
        int iA = ea + o, iB = eb + o;
        int rA = (iA < enda) ? col[iA] : NN;
        int rB = (iB < endb) ? col[iB] : NN;
        GATHER(rA, a, ua);
        GATHER(rB, b, ub);
        ea += 8; eb += 8;
    }
#undef GATHER

    // cross-octet reduction: octets differ in lane bits 3,4,5
#pragma unroll
    for (int j = 0; j < 8; ++j) {
        a[j] += __shfl_xor(a[j], 8);  b[j] += __shfl_xor(b[j], 8);
        a[j] += __shfl_xor(a[j], 16); b[j] += __shfl_xor(b[j], 16);
        a[j] += __shfl_xor(a[j], 32); b[j] += __shfl_xor(b[j], 32);
    }
    if (UMODE) {
        ua += __shfl_xor(ua, 8);  ub += __shfl_xor(ub, 8);
        ua += __shfl_xor(ua, 16); ub += __shfl_xor(ub, 16);
        ua += __shfl_xor(ua, 32); ub += __shfl_xor(ub, 32);
    }

    // octets 0/1 store node a / node b rows (8 lanes x 16 B = one 128-B row)
    if (o < 2) {
        int   n  = (o == 0) ? na : nb;
        float dv = scale[n];
        __half2 h[4];
#pragma unroll
        for (int j = 0; j < 4; ++j) {
            float x0 = (o == 0) ? a[2 * j]     : b[2 * j];
            float x1 = (o == 0) ? a[2 * j + 1] : b[2 * j + 1];
            h[j] = __halves2half2(__float2half_rn(dv * x0), __float2half_rn(dv * x1));
        }
        *(int4*)(y + (size_t)n * HH + f8) = *(int4*)h;
    }
    if (UMODE && lane < 2) {
        int n = na + lane;
        float s = ((lane == 0) ? ua : ub) * 0.125f;   // each octet counted 8x
        float dvn = dinv[n];
        float u = dvn * s;
        uout[n] = u;
        if (UMODE == 1) pout[n] = dvn * u;            // prescaled for next u-pass
    }
}

// ---------------------------------------------------------------- final GEMM
// out = (A^3 x0) @ What + u2 c0^T + u1 c1^T + 1 b2^T, split fp32 write.
#define GR 128
#define XSS 65   // +1 pad: conflict-free scalar broadcasts
__global__ __launch_bounds__(256) void k_gemm_final(
    const __half* __restrict__ y, const float* __restrict__ W,
    const float* __restrict__ b2, const float* __restrict__ cvec,
    const float* __restrict__ u1, const float* __restrict__ u2,
    float* __restrict__ out_lo, float* __restrict__ out_hi) {
    __shared__ float xs[GR * XSS];   // 33.3 KB
    __shared__ float ws[HH * HH];    // 16 KB
    int t = threadIdx.x;
    int rowBase = blockIdx.x * GR;

    {   // stage W: 1024 float4 / 256 threads
        const float4* W4 = (const float4*)W;
        float4* ws4 = (float4*)ws;
#pragma unroll
        for (int i = 0; i < 4; ++i) ws4[i * 256 + t] = W4[i * 256 + t];
    }
#pragma unroll
    for (int it = 0; it < 4; ++it) {
        int g = it * 256 + t;        // 0..1023
        int r = g >> 3;
        int c0 = (g & 7) * 8;
        int row = rowBase + r;
        if (row < NN) {
            int4 raw = *(const int4*)(y + (size_t)row * HH + c0);   // 8 halves
            __half2 h0 = *(__half2*)&raw.x, h1 = *(__half2*)&raw.y;
            __half2 h2 = *(__half2*)&raw.z, h3 = *(__half2*)&raw.w;
            float2 f0 = __half22float2(h0), f1 = __half22float2(h1);
            float2 f2 = __half22float2(h2), f3 = __half22float2(h3);
            float* dp = xs + r * XSS + c0;
            dp[0] = f0.x; dp[1] = f0.y; dp[2] = f1.x; dp[3] = f1.y;
            dp[4] = f2.x; dp[5] = f2.y; dp[6] = f3.x; dp[7] = f3.y;
        }
    }
    __syncthreads();

    int tx = t & 7;        // 8 col-groups of 8
    int ty = t >> 3;       // 32 row-groups of 4
    int j0 = tx * 8;
    int r0 = ty * 4;

    float acc[4][8];
#pragma unroll
    for (int i = 0; i < 4; ++i)
#pragma unroll
        for (int j = 0; j < 8; ++j) acc[i][j] = 0.f;

    for (int k = 0; k < HH; ++k) {
        float4 w0 = *(const float4*)(ws + k * HH + j0);
        float4 w1 = *(const float4*)(ws + k * HH + j0 + 4);
        float wv[8] = {w0.x, w0.y, w0.z, w0.w, w1.x, w1.y, w1.z, w1.w};
#pragma unroll
        for (int i = 0; i < 4; ++i) {
            float xv = xs[(r0 + i) * XSS + k];
#pragma unroll
            for (int j = 0; j < 8; ++j) acc[i][j] += xv * wv[j];
        }
    }

    float c0j[8], c1j[8], b2j[8];
#pragma unroll
    for (int j = 0; j < 8; ++j) {
        c0j[j] = cvec[j0 + j];
        c1j[j] = cvec[HH + j0 + j];
        b2j[j] = b2[j0 + j];
    }

#pragma unroll
    for (int i = 0; i < 4; ++i) {
        int r = rowBase + r0 + i;
        if (r >= NN) continue;
        float u2r = u2[r], u1r = u1[r];
        float base[8];
#pragma unroll
        for (int j = 0; j < 8; ++j) base[j] = u2r * c0j[j] + u1r * c1j[j] + b2j[j];
        float4 o0 = make_float4(acc[i][0] + base[0], acc[i][1] + base[1],
                                acc[i][2] + base[2], acc[i][3] + base[3]);
        float4 o1 = make_float4(acc[i][4] + base[4], acc[i][5] + base[5],
                                acc[i][6] + base[6], acc[i][7] + base[7]);
        float* d = (r < NU) ? (out_lo + (size_t)r * HH)
                            : (out_hi + (size_t)(r - NU) * HH);
        *(float4*)(d + j0) = o0;
        *(float4*)(d + j0 + 4) = o1;
    }
}

// ---------------------------------------------------------------- launch
extern "C" void kernel_launch(void* const* d_in, const int* in_sizes, int n_in,
                              void* d_out, int out_size, void* d_ws, size_t ws_size,
                              hipStream_t stream) {
    const int*   edge  = (const int*)d_in[0];
    const int*   src   = edge;           // edge_index[0]
    const int*   dst   = edge + NE;      // edge_index[1]
    const float* users = (const float*)d_in[1];
    const float* items = (const float*)d_in[2];
    const float* Ws    = (const float*)d_in[3];   // [3][64][64]
    const float* bs    = (const float*)d_in[4];   // [3][64]
    float*       out   = (float*)d_out;

    // workspace carve (~52 MB). Xs row NN, dinv[NN], p1u[NN] are zeroed pads
    // (k_rank block 0). state sits directly before counts: one memset covers both.
    char* w = (char*)d_ws;
    __half* Xs0     = (__half*)w; w += (size_t)(NN + 1) * HH * 2;   // 19.2 MB
    __half* Xs1     = (__half*)w; w += (size_t)(NN + 1) * HH * 2;   // 19.2 MB
    float*  dinv    = (float*)w;  w += (size_t)(NN + 1) * 4;
    float*  dinv2   = (float*)w;  w += (size_t)NN * 4;
    float*  u1      = (float*)w;  w += (size_t)NN * 4;
    float*  p1u     = (float*)w;  w += (size_t)(NN + 1) * 4;
    float*  u2      = (float*)w;  w += (size_t)NN * 4;
    float*  What    = (float*)w;  w += (size_t)HH * HH * 4;         // 16 KB
    float*  cvec    = (float*)w;  w += (size_t)2 * HH * 4;          // c0, c1
    unsigned int* state = (unsigned int*)w; w += 256 * 4;
    int*    counts  = (int*)w;    w += (size_t)NN * 4;
    int*    row_ptr = (int*)w;    w += (size_t)(NN + 1) * 4;
    w += 12;                                                  // realign to 16
    int*    col     = (int*)w;    w += (size_t)NE * 4;        // 4.8 MB
    int*    rank    = (int*)w;    w += (size_t)NE * 4;        // 4.8 MB
    (void)ws_size; (void)in_sizes; (void)n_in; (void)out_size;

    hipMemsetAsync(state, 0, (size_t)(256 + NN) * sizeof(int), stream);

    k_rank<<<(NE / 8 + 255) / 256, 256, 0, stream>>>(
        (const int4*)dst, counts, (int4*)rank,
        Xs0 + (size_t)NN * HH, Xs1 + (size_t)NN * HH, dinv, p1u);
    k_scan<<<NBLK + 1, 256, 0, stream>>>(counts, dinv, dinv2, row_ptr, state,
                                         Ws, bs, What, cvec);
    k_concat_fill<<<CONCAT_BLOCKS + FILL_BLOCKS, 256, 0, stream>>>(
        (const float4*)users, (const float4*)items, dinv, (int4*)Xs0, (float4*)out,
        (const int4*)src, (const int4*)dst, (const int4*)rank, row_ptr, col);

    // A^3 chain (u-sums folded into the gather loops) + single final gemm
    k_aggregate<1><<<AGG_BLOCKS, 256, 0, stream>>>(
        Xs0, Xs1, dinv2, row_ptr, col, dinv, dinv, u1, p1u);
    k_aggregate<2><<<AGG_BLOCKS, 256, 0, stream>>>(
        Xs1, Xs0, dinv2, row_ptr, col, dinv, p1u, u2, nullptr);
    k_aggregate<0><<<AGG_BLOCKS, 256, 0, stream>>>(
        Xs0, Xs1, dinv, row_ptr, col, nullptr, nullptr, nullptr, nullptr);

    const int GEMM_BLOCKS = (NN + GR - 1) / GR;
    k_gemm_final<<<GEMM_BLOCKS, 256, 0, stream>>>(
        Xs1, What, bs + 2 * HH, cvec, u1, u2,
        out /* x_users */, out + (size_t)2 * NU * HH /* x_items */);
}

// Round 4
// 402.971 us; speedup vs baseline: 1.0746x; 1.0023x over previous
//
#include <hip/hip_runtime.h>
#include <hip/hip_fp16.h>

#define NU 100000
#define NI 50000
#define NN 150000          // NU + NI (even)
#define HH 64
#define NE 1200000

#define SCAN_CHUNK 1024
#define NBLK ((NN + SCAN_CHUNK - 1) / SCAN_CHUNK)   // 147
#define AGG_BLOCKS (NN / 8)                          // 18750 (8 nodes/block)

#define RANK_BLOCKS   ((NE / 8 + 255) / 256)         // 587
#define CONCAT4_BLOCKS (NN * 16 / 256)               // 9375 (exact; thread = 1 float4)
#define FILL_BLOCKS   ((NE / 8 + 255) / 256)         // 586

// ---------------------------------------------------------------- rank + concat (fused)
// Two independent jobs in one dispatch, block-partitioned:
//  - rank blocks: degree histogram via atomicAdd-return (latency-bound, low
//    occupancy, 587 blocks alone can't fill 256 CUs)
//  - concat blocks: streaming passthrough + UNSCALED fp16 xs0 write (the dinv
//    prescale moved into layer-1's gather FMA, breaking the dinv dependency)
// The streaming waves soak up the issue slots the atomic waves leave idle.
// Rank block 0 also zeroes the gather pads: Xs row NN, dinv[NN], p1u[NN].
__global__ __launch_bounds__(256) void k_rank_concat(
    const int4* __restrict__ dst4, int* __restrict__ counts, int4* __restrict__ rank4,
    const float4* __restrict__ users, const float4* __restrict__ items,
    __half2* __restrict__ xs, float4* __restrict__ out,
    __half* __restrict__ pad0, __half* __restrict__ pad1,
    float* __restrict__ dinv, float* __restrict__ p1u) {
    if (blockIdx.x < RANK_BLOCKS) {
        if (blockIdx.x == 0 && threadIdx.x < 18) {
            if (threadIdx.x < 8)       ((int4*)pad0)[threadIdx.x] = make_int4(0, 0, 0, 0);
            else if (threadIdx.x < 16) ((int4*)pad1)[threadIdx.x - 8] = make_int4(0, 0, 0, 0);
            else if (threadIdx.x == 16) dinv[NN] = 0.f;
            else                        p1u[NN] = 0.f;
        }
        int t = blockIdx.x * 256 + threadIdx.x;      // over NE/8
        if (t >= NE / 8) return;
        int4 d0 = dst4[2 * t], d1 = dst4[2 * t + 1];
        int4 r0, r1;
        r0.x = atomicAdd(&counts[d0.x], 1);
        r0.y = atomicAdd(&counts[d0.y], 1);
        r0.z = atomicAdd(&counts[d0.z], 1);
        r0.w = atomicAdd(&counts[d0.w], 1);
        r1.x = atomicAdd(&counts[d1.x], 1);
        r1.y = atomicAdd(&counts[d1.y], 1);
        r1.z = atomicAdd(&counts[d1.z], 1);
        r1.w = atomicAdd(&counts[d1.w], 1);
        rank4[2 * t]     = r0;
        rank4[2 * t + 1] = r1;
    } else {
        // concat: thread = one float4 (dense lane addressing — no stride-2
        // sector replay). xs = fp16(concat(users, items)), UNSCALED.
        int i = (blockIdx.x - RANK_BLOCKS) * 256 + threadIdx.x;   // over NN*16
        const int UB = NU * 16;
        float4 v;
        if (i < UB) {
            v = users[i];
            out[UB + i] = v;                         // O1 = users_emb passthrough
        } else {
            int j = i - UB;
            v = items[j];
            out[2 * UB + NI * 16 + j] = v;           // O3 = items_emb passthrough
        }
        xs[2 * i]     = __halves2half2(__float2half_rn(v.x), __float2half_rn(v.y));
        xs[2 * i + 1] = __halves2half2(__float2half_rn(v.z), __float2half_rn(v.w));
    }
}

// ---------------------------------------------------------------- single-pass scan (decoupled lookback)
// 147 scan blocks + 1 W-combine block (148 < 256 CUs: co-resident, spin safe).
// state[b]: 0 = invalid, (1<<30)|aggregate, (2<<30)|inclusive_prefix.
// Emits dinv[n] = rsqrt(deg+1), dinv2[n] = 1/(deg+1).
// Block NBLK instead computes What = W0 W1 W2, c0 = b0^T W1 W2, c1 = b1^T W2.
__global__ __launch_bounds__(256) void k_scan(const int* __restrict__ counts,
                                              float* __restrict__ dinv,
                                              float* __restrict__ dinv2,
                                              int* __restrict__ row_ptr,
                                              unsigned int* __restrict__ state,
                                              const float* __restrict__ Wfull,
                                              const float* __restrict__ bfull,
                                              float* __restrict__ What,
                                              float* __restrict__ cvec) {
    __shared__ float smem[HH * HH];   // W12 for the combine block; 256 ints for scan
    __shared__ int s_prefix;
    int t = threadIdx.x;
    int b = blockIdx.x;

    if (b == NBLK) {
        // ---- W-combine (one block) ----
        int r = t >> 2, j0 = (t & 3) * 16;
        const float* W0 = Wfull;
        const float* W1 = Wfull + HH * HH;
        const float* W2 = Wfull + 2 * HH * HH;
        float acc[16];
#pragma unroll
        for (int j = 0; j < 16; ++j) acc[j] = 0.f;
        for (int k = 0; k < HH; ++k) {
            float a = W1[r * HH + k];
            const float* bp = W2 + k * HH + j0;
#pragma unroll
            for (int j = 0; j < 16; ++j) acc[j] += a * bp[j];
        }
#pragma unroll
        for (int j = 0; j < 16; ++j) smem[r * HH + j0 + j] = acc[j];   // W12 = W1*W2
        if (t < HH) {                       // c1 = b1^T W2
            float s = 0.f;
            for (int k = 0; k < HH; ++k) s += bfull[HH + k] * W2[k * HH + t];
            cvec[HH + t] = s;
        }
        __syncthreads();
#pragma unroll
        for (int j = 0; j < 16; ++j) acc[j] = 0.f;
        for (int k = 0; k < HH; ++k) {      // What = W0 * W12
            float a = W0[r * HH + k];
            const float* bp = smem + k * HH + j0;
#pragma unroll
            for (int j = 0; j < 16; ++j) acc[j] += a * bp[j];
        }
#pragma unroll
        for (int j = 0; j < 16; ++j) What[r * HH + j0 + j] = acc[j];
        if (t < HH) {                       // c0 = b0^T W12
            float s = 0.f;
            for (int k = 0; k < HH; ++k) s += bfull[k] * smem[k * HH + t];
            cvec[t] = s;
        }
        return;
    }

    int* sd = (int*)smem;
    int base = b * SCAN_CHUNK + t * 4;
    int c[4];
    if (base + 3 < NN) {
        int4 v = *(const int4*)(counts + base);
        c[0] = v.x; c[1] = v.y; c[2] = v.z; c[3] = v.w;
    } else {
#pragma unroll
        for (int i = 0; i < 4; ++i) c[i] = (base + i < NN) ? counts[base + i] : 0;
    }
#pragma unroll
    for (int i = 0; i < 4; ++i)
        if (base + i < NN) {
            dinv[base + i]  = rsqrtf((float)(c[i] + 1));
            dinv2[base + i] = 1.0f / (float)(c[i] + 1);
        }

    int tt = c[0] + c[1] + c[2] + c[3];
    sd[t] = tt; __syncthreads();
    for (int off = 1; off < 256; off <<= 1) {          // inclusive Hillis-Steele
        int x = (t >= off) ? sd[t - off] : 0;
        __syncthreads();
        sd[t] += x;
        __syncthreads();
    }

    if (t == 0) {
        unsigned int agg = (unsigned int)sd[255];
        if (b == 0) {
            __hip_atomic_store(&state[0], (2u << 30) | agg, __ATOMIC_RELEASE,
                               __HIP_MEMORY_SCOPE_AGENT);
            s_prefix = 0;
        } else {
            __hip_atomic_store(&state[b], (1u << 30) | agg, __ATOMIC_RELEASE,
                               __HIP_MEMORY_SCOPE_AGENT);
            unsigned int prefix = 0;
            int p = b - 1;
            while (true) {
                unsigned int s = __hip_atomic_load(&state[p], __ATOMIC_ACQUIRE,
                                                   __HIP_MEMORY_SCOPE_AGENT);
                unsigned int fl = s >> 30;
                if (fl == 0u) { __builtin_amdgcn_s_sleep(1); continue; }
                prefix += s & 0x3FFFFFFFu;
                if (fl == 2u) break;
                --p;
            }
            __hip_atomic_store(&state[b], (2u << 30) | (prefix + agg),
                               __ATOMIC_RELEASE, __HIP_MEMORY_SCOPE_AGENT);
            s_prefix = (int)prefix;
        }
    }
    __syncthreads();

    int off0 = s_prefix + (sd[t] - tt);                 // exclusive offset
    int run = 0;
#pragma unroll
    for (int i = 0; i < 4; ++i) {
        if (base + i < NN) row_ptr[base + i] = off0 + run;
        run += c[i];
    }
    if (b == NBLK - 1 && t == 0) row_ptr[NN] = NE;
}

// ---------------------------------------------------------------- CSR fill
// col[row_ptr[dst] + rank] = src. 8 edges/thread, no atomics in the chain.
__global__ __launch_bounds__(256) void k_fill(const int4* __restrict__ src4,
                                              const int4* __restrict__ dst4,
                                              const int4* __restrict__ rank4,
                                              const int* __restrict__ row_ptr,
                                              int* __restrict__ col) {
    int t = blockIdx.x * 256 + threadIdx.x;   // over NE/8
    if (t >= NE / 8) return;
    int4 s0 = src4[2 * t],  s1 = src4[2 * t + 1];
    int4 d0 = dst4[2 * t],  d1 = dst4[2 * t + 1];
    int4 r0 = rank4[2 * t], r1 = rank4[2 * t + 1];
    int p0 = row_ptr[d0.x], p1 = row_ptr[d0.y], p2 = row_ptr[d0.z], p3 = row_ptr[d0.w];
    int p4 = row_ptr[d1.x], p5 = row_ptr[d1.y], p6 = row_ptr[d1.z], p7 = row_ptr[d1.w];
    col[p0 + r0.x] = s0.x;
    col[p1 + r0.y] = s0.y;
    col[p2 + r0.z] = s0.z;
    col[p3 + r0.w] = s0.w;
    col[p4 + r1.x] = s1.x;
    col[p5 + r1.y] = s1.y;
    col[p6 + r1.z] = s1.z;
    col[p7 + r1.w] = s1.w;
}

// ---------------------------------------------------------------- aggregation (octet-gather)
// Wave = 8 octets x 8 lanes, 2 nodes/wave; lane holds 8 half-features (16 B).
// One gather instruction moves 8 rows (1 KB). Main loop unrolled x2: 4
// independent 1-KB gathers in flight per wave (latency-bound op).
// UMODE==1 (layer 1, xs UNSCALED): gather applies dinv[r] as an FMA — the
//   broadcast pin[r]=dinv[r] load is shared with the u-sum, so the prescale is
//   free. Also writes u1 = dinv.*A.dinv-col-sums and p1u = dinv*u1.
// UMODE==2: input prescaled; u-sum over pin=p1u; writes u2.
// UMODE==0: plain aggregate (input prescaled).
// u over-counts 8x (one add per octet lane); fixed by *0.125.
template <int UMODE>
__global__ __launch_bounds__(256) void k_aggregate(
    const __half* __restrict__ x, __half* __restrict__ y,
    const float* __restrict__ scale,
    const int* __restrict__ row_ptr, const int* __restrict__ col,
    const float* __restrict__ dinv, const float* __restrict__ pin,
    float* __restrict__ uout, float* __restrict__ pout) {
    int lane = threadIdx.x & 63;
    int wave = blockIdx.x * 4 + (threadIdx.x >> 6);
    int na = wave * 2;
    if (na >= NN) return;
    int nb = na + 1;                     // NN even: always valid
    int o  = lane >> 3;                  // octet 0..7 (row slot within a step)
    int f8 = (lane & 7) << 3;            // 8-feature base for this lane

    float a[8], b[8];
#pragma unroll
    for (int j = 0; j < 8; ++j) { a[j] = 0.f; b[j] = 0.f; }
    float ua = 0.f, ub = 0.f;

#define GATHER(r, acc, uacc)                                               \
    {                                                                      \
        int4 raw = *(const int4*)(x + (size_t)(r) * HH + f8);              \
        float dr = 1.f;                                                    \
        if (UMODE) { dr = pin[r]; uacc += dr; }                            \
        __half2* hp = (__half2*)&raw;                                      \
        _Pragma("unroll")                                                  \
        for (int j = 0; j < 4; ++j) {                                      \
            float2 f = __half22float2(hp[j]);                              \
            if (UMODE == 1) { acc[2 * j] += dr * f.x; acc[2 * j + 1] += dr * f.y; } \
            else            { acc[2 * j] += f.x;      acc[2 * j + 1] += f.y; }      \
        }                                                                  \
    }

    int ea = row_ptr[na], enda = row_ptr[na + 1];
    int eb = enda,        endb = row_ptr[nb + 1];   // rows adjacent

    // prologue: octet 0 = self row, octets 1-7 = first 7 edges (pad -> NN)
    {
        int ia = ea + o - 1;
        int ib = eb + o - 1;
        int rA = (o == 0) ? na : ((ia < enda) ? col[ia] : NN);
        int rB = (o == 0) ? nb : ((ib < endb) ? col[ib] : NN);
        GATHER(rA, a, ua);
        GATHER(rB, b, ub);
        ea += 7; eb += 7;
    }
    // main loop, unrolled x2: 16 edges per node per iteration
    while (ea < enda || eb < endb) {
        int iA0 = ea + o,     iA1 = ea + 8 + o;
        int iB0 = eb + o,     iB1 = eb + 8 + o;
        int rA0 = (iA0 < enda) ? col[iA0] : NN;
        int rA1 = (iA1 < enda) ? col[iA1] : NN;
        int rB0 = (iB0 < endb) ? col[iB0] : NN;
        int rB1 = (iB1 < endb) ? col[iB1] : NN;
        GATHER(rA0, a, ua);
        GATHER(rA1, a, ua);
        GATHER(rB0, b, ub);
        GATHER(rB1, b, ub);
        ea += 16; eb += 16;
    }
#undef GATHER

    // cross-octet reduction: octets differ in lane bits 3,4,5
#pragma unroll
    for (int j = 0; j < 8; ++j) {
        a[j] += __shfl_xor(a[j], 8);  b[j] += __shfl_xor(b[j], 8);
        a[j] += __shfl_xor(a[j], 16); b[j] += __shfl_xor(b[j], 16);
        a[j] += __shfl_xor(a[j], 32); b[j] += __shfl_xor(b[j], 32);
    }
    if (UMODE) {
        ua += __shfl_xor(ua, 8);  ub += __shfl_xor(ub, 8);
        ua += __shfl_xor(ua, 16); ub += __shfl_xor(ub, 16);
        ua += __shfl_xor(ua, 32); ub += __shfl_xor(ub, 32);
    }

    // octets 0/1 store node a / node b rows (8 lanes x 16 B = one 128-B row)
    if (o < 2) {
        int   n  = (o == 0) ? na : nb;
        float dv = scale[n];
        __half2 h[4];
#pragma unroll
        for (int j = 0; j < 4; ++j) {
            float x0 = (o == 0) ? a[2 * j]     : b[2 * j];
            float x1 = (o == 0) ? a[2 * j + 1] : b[2 * j + 1];
            h[j] = __halves2half2(__float2half_rn(dv * x0), __float2half_rn(dv * x1));
        }
        *(int4*)(y + (size_t)n * HH + f8) = *(int4*)h;
    }
    if (UMODE && lane < 2) {
        int n = na + lane;
        float s = ((lane == 0) ? ua : ub) * 0.125f;   // each octet counted 8x
        float dvn = dinv[n];
        float u = dvn * s;
        uout[n] = u;
        if (UMODE == 1) pout[n] = dvn * u;            // prescaled for next u-pass
    }
}

// ---------------------------------------------------------------- final GEMM
// out = (A^3 x0) @ What + u2 c0^T + u1 c1^T + 1 b2^T, split fp32 write.
#define GR 128
#define XSS 65   // +1 pad: conflict-free scalar broadcasts
__global__ __launch_bounds__(256) void k_gemm_final(
    const __half* __restrict__ y, const float* __restrict__ W,
    const float* __restrict__ b2, const float* __restrict__ cvec,
    const float* __restrict__ u1, const float* __restrict__ u2,
    float* __restrict__ out_lo, float* __restrict__ out_hi) {
    __shared__ float xs[GR * XSS];   // 33.3 KB
    __shared__ float ws[HH * HH];    // 16 KB
    int t = threadIdx.x;
    int rowBase = blockIdx.x * GR;

    {   // stage W: 1024 float4 / 256 threads
        const float4* W4 = (const float4*)W;
        float4* ws4 = (float4*)ws;
#pragma unroll
        for (int i = 0; i < 4; ++i) ws4[i * 256 + t] = W4[i * 256 + t];
    }
#pragma unroll
    for (int it = 0; it < 4; ++it) {
        int g = it * 256 + t;        // 0..1023
        int r = g >> 3;
        int c0 = (g & 7) * 8;
        int row = rowBase + r;
        if (row < NN) {
            int4 raw = *(const int4*)(y + (size_t)row * HH + c0);   // 8 halves
            __half2 h0 = *(__half2*)&raw.x, h1 = *(__half2*)&raw.y;
            __half2 h2 = *(__half2*)&raw.z, h3 = *(__half2*)&raw.w;
            float2 f0 = __half22float2(h0), f1 = __half22float2(h1);
            float2 f2 = __half22float2(h2), f3 = __half22float2(h3);
            float* dp = xs + r * XSS + c0;
            dp[0] = f0.x; dp[1] = f0.y; dp[2] = f1.x; dp[3] = f1.y;
            dp[4] = f2.x; dp[5] = f2.y; dp[6] = f3.x; dp[7] = f3.y;
        }
    }
    __syncthreads();

    int tx = t & 7;        // 8 col-groups of 8
    int ty = t >> 3;       // 32 row-groups of 4
    int j0 = tx * 8;
    int r0 = ty * 4;

    float acc[4][8];
#pragma unroll
    for (int i = 0; i < 4; ++i)
#pragma unroll
        for (int j = 0; j < 8; ++j) acc[i][j] = 0.f;

    for (int k = 0; k < HH; ++k) {
        float4 w0 = *(const float4*)(ws + k * HH + j0);
        float4 w1 = *(const float4*)(ws + k * HH + j0 + 4);
        float wv[8] = {w0.x, w0.y, w0.z, w0.w, w1.x, w1.y, w1.z, w1.w};
#pragma unroll
        for (int i = 0; i < 4; ++i) {
            float xv = xs[(r0 + i) * XSS + k];
#pragma unroll
            for (int j = 0; j < 8; ++j) acc[i][j] += xv * wv[j];
        }
    }

    float c0j[8], c1j[8], b2j[8];
#pragma unroll
    for (int j = 0; j < 8; ++j) {
        c0j[j] = cvec[j0 + j];
        c1j[j] = cvec[HH + j0 + j];
        b2j[j] = b2[j0 + j];
    }

#pragma unroll
    for (int i = 0; i < 4; ++i) {
        int r = rowBase + r0 + i;
        if (r >= NN) continue;
        float u2r = u2[r], u1r = u1[r];
        float base[8];
#pragma unroll
        for (int j = 0; j < 8; ++j) base[j] = u2r * c0j[j] + u1r * c1j[j] + b2j[j];
        float4 o0 = make_float4(acc[i][0] + base[0], acc[i][1] + base[1],
                                acc[i][2] + base[2], acc[i][3] + base[3]);
        float4 o1 = make_float4(acc[i][4] + base[4], acc[i][5] + base[5],
                                acc[i][6] + base[6], acc[i][7] + base[7]);
        float* d = (r < NU) ? (out_lo + (size_t)r * HH)
                            : (out_hi + (size_t)(r - NU) * HH);
        *(float4*)(d + j0) = o0;
        *(float4*)(d + j0 + 4) = o1;
    }
}

// ---------------------------------------------------------------- launch
extern "C" void kernel_launch(void* const* d_in, const int* in_sizes, int n_in,
                              void* d_out, int out_size, void* d_ws, size_t ws_size,
                              hipStream_t stream) {
    const int*   edge  = (const int*)d_in[0];
    const int*   src   = edge;           // edge_index[0]
    const int*   dst   = edge + NE;      // edge_index[1]
    const float* users = (const float*)d_in[1];
    const float* items = (const float*)d_in[2];
    const float* Ws    = (const float*)d_in[3];   // [3][64][64]
    const float* bs    = (const float*)d_in[4];   // [3][64]
    float*       out   = (float*)d_out;

    // workspace carve (~52 MB). Xs row NN, dinv[NN], p1u[NN] are zeroed pads
    // (rank block 0). state sits directly before counts: one memset covers both.
    char* w = (char*)d_ws;
    __half* Xs0     = (__half*)w; w += (size_t)(NN + 1) * HH * 2;   // 19.2 MB
    __half* Xs1     = (__half*)w; w += (size_t)(NN + 1) * HH * 2;   // 19.2 MB
    float*  dinv    = (float*)w;  w += (size_t)(NN + 1) * 4;
    float*  dinv2   = (float*)w;  w += (size_t)NN * 4;
    float*  u1      = (float*)w;  w += (size_t)NN * 4;
    float*  p1u     = (float*)w;  w += (size_t)(NN + 1) * 4;
    float*  u2      = (float*)w;  w += (size_t)NN * 4;
    float*  What    = (float*)w;  w += (size_t)HH * HH * 4;         // 16 KB
    float*  cvec    = (float*)w;  w += (size_t)2 * HH * 4;          // c0, c1
    unsigned int* state = (unsigned int*)w; w += 256 * 4;
    int*    counts  = (int*)w;    w += (size_t)NN * 4;
    int*    row_ptr = (int*)w;    w += (size_t)(NN + 1) * 4;
    w += 12;                                                  // realign to 16
    int*    col     = (int*)w;    w += (size_t)NE * 4;        // 4.8 MB
    int*    rank    = (int*)w;    w += (size_t)NE * 4;        // 4.8 MB
    (void)ws_size; (void)in_sizes; (void)n_in; (void)out_size;

    hipMemsetAsync(state, 0, (size_t)(256 + NN) * sizeof(int), stream);

    k_rank_concat<<<RANK_BLOCKS + CONCAT4_BLOCKS, 256, 0, stream>>>(
        (const int4*)dst, counts, (int4*)rank,
        (const float4*)users, (const float4*)items, (__half2*)Xs0, (float4*)out,
        Xs0 + (size_t)NN * HH, Xs1 + (size_t)NN * HH, dinv, p1u);
    k_scan<<<NBLK + 1, 256, 0, stream>>>(counts, dinv, dinv2, row_ptr, state,
                                         Ws, bs, What, cvec);
    k_fill<<<FILL_BLOCKS, 256, 0, stream>>>(
        (const int4*)src, (const int4*)dst, (const int4*)rank, row_ptr, col);

    // A^3 chain (u-sums + layer-1 dinv prescale folded into the gather loops)
    k_aggregate<1><<<AGG_BLOCKS, 256, 0, stream>>>(
        Xs0, Xs1, dinv2, row_ptr, col, dinv, dinv, u1, p1u);
    k_aggregate<2><<<AGG_BLOCKS, 256, 0, stream>>>(
        Xs1, Xs0, dinv2, row_ptr, col, dinv, p1u, u2, nullptr);
    k_aggregate<0><<<AGG_BLOCKS, 256, 0, stream>>>(
        Xs0, Xs1, dinv, row_ptr, col, nullptr, nullptr, nullptr, nullptr);

    const int GEMM_BLOCKS = (NN + GR - 1) / GR;
    k_gemm_final<<<GEMM_BLOCKS, 256, 0, stream>>>(
        Xs1, What, bs + 2 * HH, cvec, u1, u2,
        out /* x_users */, out + (size_t)2 * NU * HH /* x_items */);
}